// Round 3
// baseline (115124.365 us; speedup 1.0000x reference)
//
#include <hip/hip_runtime.h>

#define BDIM 128
#define TDIM 1024
#define HDIM 256

// R14 "bslice": batch-sliced GRU — zero inter-WG communication.
// 8 WGs x 512 threads (8 waves); WG owns 16 batch rows for all layers,
// head, and all 1024 steps. h state (digit-split bf16) lives in LDS.
// Weights digit-packed in ws (L2-resident per XCD, ~3.9 MB read-only).
// Layer math is bit-identical to the R11-verified digit pipeline.

#define XF_OFF    0u          // fp32 x features [B][T][6]   = 3145728 B
#define DONEF_OFF 3145728u    // fp32 done [B][T]            = 524288 B
#define WPK_OFF   3670016u    // bf16 digit-packed {wh0,wi1,wh1,wi2,wh2} = 3932160 B
#define HPK_OFF   7602176u    // bf16 digit-packed head (32x256)          = 65536 B
#define WI0F_OFF  7667712u    // fp32 wi0 (768x6) = 18432 B
#define BIAS_OFF  7686144u    // fp32 {bi0,bh0,bi1,bh1,bi2,bh2} = 18432 B
#define BFY_OFF   7704576u    // fp32 bfy (30)
#define BFP_OFF   7704704u    // fp32 bfp (1)
#define WS_NEEDED 7704708u

#define MAT_STRIDE 786432u    // 48nt*8it*2dw*1024B per packed matrix
#define PL   8448             // LDS plane bytes: 16 rows * 264 bf16 * 2B
#define ROWB 528              // LDS row bytes

typedef __attribute__((ext_vector_type(8))) short bf16x8;
typedef __attribute__((ext_vector_type(4))) float f32x4;

template <int N> struct IC { static constexpr int v = N; };

static __device__ __forceinline__ unsigned short f2bf(float f) {
  union { float f; unsigned u; } v; v.f = f;
  unsigned r = v.u + 0x7fffu + ((v.u >> 16) & 1u);   // RNE
  return (unsigned short)(r >> 16);
}
static __device__ __forceinline__ float bf2f(unsigned short h) {
  union { unsigned u; float f; } v; v.u = ((unsigned)h) << 16;
  return v.f;
}
static __device__ __forceinline__ float sigm(float x) { return 1.f / (1.f + __expf(-x)); }
static __device__ __forceinline__ float tanha(float x) { return 1.f - 2.f / (1.f + __expf(2.f * x)); }

__global__ void diag_kernel(float* out, float code) {
  if (threadIdx.x == 0 && blockIdx.x == 0) out[0] = code;
}

// ---------- prep: pack weights into MFMA B-fragment digit layout ----------
// Packed chunk addressing: byte = ((((mat*48+nt)*8+it)*2+dw)*64 + lane)*16
// holds W_dw[nt*16 + (lane&15)][it*32 + (lane>>4)*8 + e], e=0..7 as bf16.
__global__ void prep_kernel(const float* __restrict__ rew, const float* __restrict__ done,
                            const float* __restrict__ gamma, const float* __restrict__ prob,
                            const float* __restrict__ y, const float* __restrict__ y1,
                            const float* __restrict__ w_e1, const float* __restrict__ b_e1,
                            const float* __restrict__ w_e2, const float* __restrict__ b_e2,
                            const float* __restrict__ wi0, const float* __restrict__ wh0,
                            const float* __restrict__ bi0, const float* __restrict__ bh0,
                            const float* __restrict__ wi1, const float* __restrict__ wh1,
                            const float* __restrict__ bi1, const float* __restrict__ bh1,
                            const float* __restrict__ wi2, const float* __restrict__ wh2,
                            const float* __restrict__ bi2, const float* __restrict__ bh2,
                            const float* __restrict__ wfy, const float* __restrict__ bfy,
                            const float* __restrict__ wfp, const float* __restrict__ bfp,
                            char* __restrict__ ws) {
  float* wi0f  = (float*)(ws + WI0F_OFF);
  float* bias  = (float*)(ws + BIAS_OFF);
  float* bfyf  = (float*)(ws + BFY_OFF);
  float* bfpf  = (float*)(ws + BFP_OFF);
  float* donef = (float*)(ws + DONEF_OFF);
  float* xfeat = (float*)(ws + XF_OFF);
  unsigned short* wpk16 = (unsigned short*)(ws + WPK_OFF);
  unsigned short* hpk16 = (unsigned short*)(ws + HPK_OFF);

  __shared__ float we1[480], be1[16], we2[16];
  __shared__ float be2s, gam;
  for (int i = threadIdx.x; i < 480; i += blockDim.x) we1[i] = w_e1[i];
  if (threadIdx.x < 16) { be1[threadIdx.x] = b_e1[threadIdx.x]; we2[threadIdx.x] = w_e2[threadIdx.x]; }
  if (threadIdx.x == 0) { be2s = b_e2[0]; gam = gamma[0]; }
  __syncthreads();
  const int gid = blockIdx.x * blockDim.x + threadIdx.x;
  const int stride = gridDim.x * blockDim.x;

  // 5 layer matrices: {wh0, wi1, wh1, wi2, wh2}, 393216 u16 each
  for (int o = gid; o < 1966080; o += stride) {
    const int e = o & 7; int r = o >> 3;
    const int ln = r & 63; r >>= 6;
    const int dw = r & 1; r >>= 1;
    const int it = r & 7; r >>= 3;
    const int nt = r % 48; const int mat = r / 48;
    const int row = nt * 16 + (ln & 15);
    const int col = it * 32 + (ln >> 4) * 8 + e;
    const float* W = (mat == 0) ? wh0 : (mat == 1) ? wi1 : (mat == 2) ? wh1
                   : (mat == 3) ? wi2 : wh2;
    const float v = W[row * 256 + col];
    const unsigned short d1 = f2bf(v);
    wpk16[o] = dw ? f2bf(v - bf2f(d1)) : d1;
  }
  // head matrix: rows 0..29 = wfy, 30 = wfp, 31 = 0
  for (int o = gid; o < 32768; o += stride) {
    const int e = o & 7; int r = o >> 3;
    const int ln = r & 63; r >>= 6;
    const int dw = r & 1; r >>= 1;
    const int it = r & 7; r >>= 3;
    const int nt = r & 1;
    const int row = nt * 16 + (ln & 15);
    const int col = it * 32 + (ln >> 4) * 8 + e;
    const float v = (row < 30) ? wfy[row * 256 + col] : ((row == 30) ? wfp[col] : 0.f);
    const unsigned short d1 = f2bf(v);
    hpk16[o] = dw ? f2bf(v - bf2f(d1)) : d1;
  }

  for (int i = gid; i < 4608; i += stride) wi0f[i] = wi0[i];
  for (int i = gid; i < 768; i += stride) {
    bias[i]           = bi0[i];
    bias[768 + i]     = bh0[i];
    bias[2 * 768 + i] = bi1[i];
    bias[3 * 768 + i] = bh1[i];
    bias[4 * 768 + i] = bi2[i];
    bias[5 * 768 + i] = bh2[i];
  }
  for (int i = gid; i < 30; i += stride) bfyf[i] = bfy[i];
  if (gid == 0) bfpf[0] = bfp[0];
  for (int i = gid; i < BDIM * TDIM; i += stride) donef[i] = done[i];

  for (int i = gid; i < BDIM * TDIM; i += stride) {   // i = b*T + t
    float yr[30], y1r[30];
    #pragma unroll
    for (int c = 0; c < 30; ++c) { yr[c] = y[(size_t)i * 30 + c]; y1r[c] = y1[(size_t)i * 30 + c]; }
    float a0 = 0.f, a1 = 0.f;
    #pragma unroll 4
    for (int jm = 0; jm < 16; ++jm) {
      float s0 = be1[jm], s1 = be1[jm];
      #pragma unroll
      for (int c = 0; c < 30; ++c) { float w = we1[jm * 30 + c]; s0 += yr[c] * w; s1 += y1r[c] * w; }
      a0 += fmaxf(s0, 0.f) * we2[jm];
      a1 += fmaxf(s1, 0.f) * we2[jm];
    }
    float* xr = xfeat + (size_t)i * 6;
    xr[0] = rew[i]; xr[1] = done[i]; xr[2] = gam;
    xr[3] = prob[i]; xr[4] = sigm(a0 + be2s); xr[5] = sigm(a1 + be2s);
  }
}

// ---------------- main: 8 WGs, each fully local over its 16 batch rows ----------
// LDS planes: [layer 0..2][digit 0..1] of [16 rows][264 bf16] (pad 264 =>
// ds_read_b128 at floor-optimal bank utilization). Per step:
//   L0: reads plane0 (h0(t-1)) -> bar -> writes plane0 (h0(t)) -> bar
//   L1: reads plane1 (h1(t-1)) + plane0 (h0(t)) -> bar -> writes plane1 -> bar
//   L2: reads plane2 + plane1 -> bar -> writes plane2 -> bar
//   head (waves 0-1): reads plane2, stores outputs (no barrier needed; next
//   write of plane2 is >=5 barriers away).
__global__ void __launch_bounds__(512, 1) gru_main(char* __restrict__ ws,
                                                   float* __restrict__ out) {
  __shared__ char hlds[6 * PL];
  const int tid = threadIdx.x;
  const int wg = blockIdx.x;
  const int wv = tid >> 6, lane = tid & 63, q = lane >> 4, jj = lane & 15;

  const float* donef = (const float*)(ws + DONEF_OFF);
  const float* xfeat = (const float*)(ws + XF_OFF);
  const char*  wpk   = (const char*)(ws + WPK_OFF);
  const char*  hpk   = (const char*)(ws + HPK_OFF);
  const float* wi0f  = (const float*)(ws + WI0F_OFF);
  const float* bias  = (const float*)(ws + BIAS_OFF);
  const float* bfy   = (const float*)(ws + BFY_OFF);
  const float* bfp   = (const float*)(ws + BFP_OFF);

  for (int i = tid; i < (6 * PL) / 4; i += 512) ((unsigned*)hlds)[i] = 0u;

  const int gbase = wv * 32;          // this wave's 32-gate slice
  float biv[3][3][2], bhv[3][3][2];   // [layer][gate-type][sub-tile]
  #pragma unroll
  for (int l = 0; l < 3; ++l)
    #pragma unroll
    for (int gt = 0; gt < 3; ++gt)
      #pragma unroll
      for (int st = 0; st < 2; ++st) {
        const int g = gbase + st * 16 + jj;
        biv[l][gt][st] = bias[2 * l * 768 + gt * 256 + g];
        bhv[l][gt][st] = bias[(2 * l + 1) * 768 + gt * 256 + g];
      }
  float wx0v[3][2][6];
  #pragma unroll
  for (int gt = 0; gt < 3; ++gt)
    #pragma unroll
    for (int st = 0; st < 2; ++st) {
      const int g = gbase + st * 16 + jj;
      #pragma unroll
      for (int c = 0; c < 6; ++c) wx0v[gt][st][c] = wi0f[(gt * 256 + g) * 6 + c];
    }
  const int dh = wv * 16 + jj;        // head output index (waves 0-1)
  const float hbias = (wv < 2) ? ((dh < 30) ? bfy[dh] : ((dh == 30) ? bfp[0] : 0.f)) : 0.f;

  float hc[3][8];                     // fp32 carry [layer][st*4+i]
  #pragma unroll
  for (int l = 0; l < 3; ++l)
    #pragma unroll
    for (int i = 0; i < 8; ++i) hc[l][i] = 0.f;

  const int bb0 = wg * 16;            // batch base
  const int aoff = jj * ROWB + q * 16; // A-frag base byte in a plane
  const f32x4 z4 = {0.f, 0.f, 0.f, 0.f};
  __syncthreads();

  float sF[4];
  float xf[4][6];

  auto do_layer = [&](auto lc) {
    constexpr int L = decltype(lc)::v;
    constexpr int MH = (L == 0) ? 0 : ((L == 1) ? 2 : 4);
    char* plH0 = hlds + (L * 2 + 0) * PL;
    char* plH1 = hlds + (L * 2 + 1) * PL;
    const char* wh = wpk + (size_t)MH * MAT_STRIDE;

    f32x4 C[3][2], X[3][2];
    #pragma unroll
    for (int gt = 0; gt < 3; ++gt)
      #pragma unroll
      for (int st = 0; st < 2; ++st) { C[gt][st] = z4; X[gt][st] = z4; }

    #pragma unroll
    for (int it = 0; it < 8; ++it) {
      const bf16x8 ah0 = *(const bf16x8*)(plH0 + aoff + it * 64);
      const bf16x8 ah1 = *(const bf16x8*)(plH1 + aoff + it * 64);
      bf16x8 ax0{}, ax1{};
      if constexpr (L > 0) {
        const char* plX0 = hlds + ((L - 1) * 2 + 0) * PL;
        const char* plX1 = hlds + ((L - 1) * 2 + 1) * PL;
        ax0 = *(const bf16x8*)(plX0 + aoff + it * 64);
        ax1 = *(const bf16x8*)(plX1 + aoff + it * 64);
      }
      #pragma unroll
      for (int gt = 0; gt < 3; ++gt) {
        #pragma unroll
        for (int st = 0; st < 2; ++st) {
          const int nt = gt * 16 + wv * 2 + st;
          const char* bp = wh + (size_t)((nt * 8 + it) * 2) * 1024 + lane * 16;
          const bf16x8 b0 = *(const bf16x8*)bp;
          const bf16x8 b1 = *(const bf16x8*)(bp + 1024);
          C[gt][st] = __builtin_amdgcn_mfma_f32_16x16x32_bf16(ah0, b0, C[gt][st], 0, 0, 0);
          C[gt][st] = __builtin_amdgcn_mfma_f32_16x16x32_bf16(ah1, b0, C[gt][st], 0, 0, 0);
          C[gt][st] = __builtin_amdgcn_mfma_f32_16x16x32_bf16(ah0, b1, C[gt][st], 0, 0, 0);
          C[gt][st] = __builtin_amdgcn_mfma_f32_16x16x32_bf16(ah1, b1, C[gt][st], 0, 0, 0);
          if constexpr (L > 0) {
            constexpr int MX = (L == 1) ? 1 : 3;
            const char* xp = wpk + (size_t)MX * MAT_STRIDE
                           + (size_t)((nt * 8 + it) * 2) * 1024 + lane * 16;
            const bf16x8 c0 = *(const bf16x8*)xp;
            const bf16x8 c1 = *(const bf16x8*)(xp + 1024);
            X[gt][st] = __builtin_amdgcn_mfma_f32_16x16x32_bf16(ax0, c0, X[gt][st], 0, 0, 0);
            X[gt][st] = __builtin_amdgcn_mfma_f32_16x16x32_bf16(ax1, c0, X[gt][st], 0, 0, 0);
            X[gt][st] = __builtin_amdgcn_mfma_f32_16x16x32_bf16(ax0, c1, X[gt][st], 0, 0, 0);
            X[gt][st] = __builtin_amdgcn_mfma_f32_16x16x32_bf16(ax1, c1, X[gt][st], 0, 0, 0);
          }
        }
      }
    }

    __syncthreads();   // all waves done READING planes before any write

    // epilogue (C/D layout: row = q*4+i -> batch, col = jj -> gate)
    #pragma unroll
    for (int st = 0; st < 2; ++st) {
      #pragma unroll
      for (int i = 0; i < 4; ++i) {
        const float s1 = sF[i];
        float gxr, gxz, gxn;
        if constexpr (L == 0) {
          gxr = 0.f; gxz = 0.f; gxn = 0.f;
          #pragma unroll
          for (int c = 0; c < 6; ++c) {
            const float xv = xf[i][c];
            gxr += xv * wx0v[0][st][c];
            gxz += xv * wx0v[1][st][c];
            gxn += xv * wx0v[2][st][c];
          }
        } else {
          gxr = X[0][st][i]; gxz = X[1][st][i]; gxn = X[2][st][i];
        }
        const float r = sigm(gxr + biv[L][0][st] + s1 * C[0][st][i] + bhv[L][0][st]);
        const float z = sigm(gxz + biv[L][1][st] + s1 * C[1][st][i] + bhv[L][1][st]);
        const float n = tanha(gxn + biv[L][2][st] + r * (s1 * C[2][st][i] + bhv[L][2][st]));
        const float hp = hc[L][st * 4 + i] * s1;
        const float hv = (1.f - z) * n + z * hp;
        hc[L][st * 4 + i] = hv;
        const unsigned short d1 = f2bf(hv);
        const unsigned short d2 = f2bf(hv - bf2f(d1));
        const int off = (q * 4 + i) * ROWB + (gbase + st * 16 + jj) * 2;
        *(unsigned short*)(plH0 + off) = d1;
        *(unsigned short*)(plH1 + off) = d2;
      }
    }
    __syncthreads();   // writes visible before next phase reads
  };

  for (int s = 0; s < 1024; ++s) {
    const int t = 1023 - s;
    #pragma unroll
    for (int i = 0; i < 4; ++i) {
      const int b = bb0 + q * 4 + i;
      sF[i] = 1.f - donef[b * 1024 + t];
      #pragma unroll
      for (int c = 0; c < 6; ++c) xf[i][c] = xfeat[((size_t)b * 1024 + t) * 6 + c];
    }

    do_layer(IC<0>{});
    do_layer(IC<1>{});
    do_layer(IC<2>{});

    // head: waves 0-1 compute the 31 outputs for the WG's 16 batch rows
    if (wv < 2) {
      const char* plH0 = hlds + (2 * 2 + 0) * PL;
      const char* plH1 = hlds + (2 * 2 + 1) * PL;
      f32x4 Ch = z4;
      #pragma unroll
      for (int it = 0; it < 8; ++it) {
        const bf16x8 a0 = *(const bf16x8*)(plH0 + aoff + it * 64);
        const bf16x8 a1 = *(const bf16x8*)(plH1 + aoff + it * 64);
        const char* bp = hpk + (size_t)(((wv * 8) + it) * 2) * 1024 + lane * 16;
        const bf16x8 b0 = *(const bf16x8*)bp;
        const bf16x8 b1 = *(const bf16x8*)(bp + 1024);
        Ch = __builtin_amdgcn_mfma_f32_16x16x32_bf16(a0, b0, Ch, 0, 0, 0);
        Ch = __builtin_amdgcn_mfma_f32_16x16x32_bf16(a1, b0, Ch, 0, 0, 0);
        Ch = __builtin_amdgcn_mfma_f32_16x16x32_bf16(a0, b1, Ch, 0, 0, 0);
        Ch = __builtin_amdgcn_mfma_f32_16x16x32_bf16(a1, b1, Ch, 0, 0, 0);
      }
      #pragma unroll
      for (int i = 0; i < 4; ++i) {
        const int b = bb0 + q * 4 + i;
        const float acc = Ch[i] + hbias;
        if (dh < 30)        out[131072 + ((size_t)b * 1024 + t) * 30 + dh] = sigm(acc);
        else if (dh == 30)  out[(size_t)b * 1024 + t] = acc;
      }
    }
    // next plane-2 write is >=5 barriers away; no trailing barrier needed
  }
}

extern "C" void kernel_launch(void* const* d_in, const int* in_sizes, int n_in,
                              void* d_out, int out_size, void* d_ws, size_t ws_size,
                              hipStream_t stream) {
  static const int EXP_SIZES[26] = {131072, 131072, 1, 131072, 3932160, 3932160,
                                    4608, 196608, 768, 768,
                                    196608, 196608, 768, 768,
                                    196608, 196608, 768, 768,
                                    7680, 30, 256, 1, 480, 16, 16, 1};
  float code = 0.f;
  if (n_in != 26) code = 900.f;
  if (code == 0.f) {
    for (int i = 0; i < 26; ++i)
      if (in_sizes[i] != EXP_SIZES[i]) { code = 100.f + 4.f * (float)i; break; }
  }
  if (code == 0.f && out_size != 4063232) code = 400.f;
  if (code == 0.f && ws_size < (size_t)WS_NEEDED) code = 300.f;
  if (code != 0.f) {
    diag_kernel<<<1, 64, 0, stream>>>((float*)d_out, code);
    return;
  }

  char* ws = (char*)d_ws;
  prep_kernel<<<512, 256, 0, stream>>>(
      (const float*)d_in[0], (const float*)d_in[1], (const float*)d_in[2],
      (const float*)d_in[3], (const float*)d_in[4], (const float*)d_in[5],
      (const float*)d_in[22], (const float*)d_in[23], (const float*)d_in[24], (const float*)d_in[25],
      (const float*)d_in[6], (const float*)d_in[7], (const float*)d_in[8], (const float*)d_in[9],
      (const float*)d_in[10], (const float*)d_in[11], (const float*)d_in[12], (const float*)d_in[13],
      (const float*)d_in[14], (const float*)d_in[15], (const float*)d_in[16], (const float*)d_in[17],
      (const float*)d_in[18], (const float*)d_in[19], (const float*)d_in[20], (const float*)d_in[21],
      ws);
  gru_main<<<8, 512, 0, stream>>>(ws, (float*)d_out);
}

// Round 4
// 18082.434 us; speedup vs baseline: 6.3666x; 6.3666x over previous
//
#include <hip/hip_runtime.h>

#define BDIM 128
#define TDIM 1024
#define HDIM 256
#define SLOT (BDIM*HDIM)
#define NWG_TOTAL 64              // 48 layer (3 x 16 j-slices) + 16 head
#define RING 14                   // h-plane ring depth per layer (was 3)

// ws byte offsets — weights/biases now read DIRECTLY from d_in (no mirrors),
// hf2 fp32 ring removed (head reconstructs from digit planes).
#define FLAGS_OFF 0u              // u32 flag per (group g<4, wg<16) at u32 idx (g*16+w)*8
#define HD_OFF    2048u           // bf16 h digit planes [(l*RING+slot)*2+dig][B*H]
                                  //   = 3*14*2*65536 = 5,505,024 B
#define XF_OFF    5507072u        // fp32 x features [B][T][6] = 3,145,728 B
#define DONEF_OFF 8652800u        // fp32 done [B][T] = 524,288 B
#define WS_NEEDED 9177088u
#define NZERO_U32 1376768         // (2048 + 5505024)/4 — flags + hd planes

typedef __attribute__((ext_vector_type(8))) short bf16x8;
typedef __attribute__((ext_vector_type(4))) float f32x4;

static __device__ __forceinline__ unsigned short f2bf(float f) {
  union { float f; unsigned u; } v; v.f = f;
  unsigned r = v.u + 0x7fffu + ((v.u >> 16) & 1u);   // RNE
  return (unsigned short)(r >> 16);
}
static __device__ __forceinline__ float bf2f(unsigned short h) {
  union { unsigned u; float f; } v; v.u = ((unsigned)h) << 16;
  return v.f;
}
static __device__ __forceinline__ float sigm(float x) { return 1.f / (1.f + __expf(-x)); }
static __device__ __forceinline__ float tanha(float x) { return 1.f - 2.f / (1.f + __expf(2.f * x)); }

// data-plane coherence (R12-proven): relaxed agent atomics
static __device__ __forceinline__ unsigned long long ld_u64_coh(const void* p) {
  return __hip_atomic_load((const unsigned long long*)p, __ATOMIC_RELAXED, __HIP_MEMORY_SCOPE_AGENT);
}
static __device__ __forceinline__ void st_u32_coh(void* p, unsigned v) {
  __hip_atomic_store((unsigned*)p, v, __ATOMIC_RELAXED, __HIP_MEMORY_SCOPE_AGENT);
}
static __device__ __forceinline__ bf16x8 ld_frag_coh(const unsigned short* p) {
  union { bf16x8 v; unsigned long long q[2]; } u;
  u.q[0] = ld_u64_coh(p);
  u.q[1] = ld_u64_coh(p + 4);
  return u.v;
}

// flags: SYSTEM scope (lowers with sc0 sc1 -> bypasses per-XCD L2 both ways;
// targets flag-visibility latency D directly)
static __device__ __forceinline__ unsigned poll_flag(const unsigned* p) {
  return __hip_atomic_load(p, __ATOMIC_RELAXED, __HIP_MEMORY_SCOPE_SYSTEM);
}
static __device__ __forceinline__ void post_flag(unsigned* fl, int g, int w, int s1) {
  __hip_atomic_store(fl + (g * 16 + w) * 8, (unsigned)s1, __ATOMIC_RELAXED, __HIP_MEMORY_SCOPE_SYSTEM);
}

// Wave-autonomous dataflow wait: lanes 0-15 check group g0, 16-31 g1,
// 32-47 g2, 48-63 idle. target<=0 => auto-true. skipw: own flag auto-true.
static __device__ __forceinline__ void wave_wait(unsigned* fl,
                                                 int g0, int t0,
                                                 int g1, int t1,
                                                 int g2, int t2,
                                                 int skipw) {
  const int lane = threadIdx.x & 63;
  const int sel = lane >> 4;
  const int w = lane & 15;
  int g = g0, tgt = t0;
  if (sel == 1) { g = g1; tgt = t1; }
  if (sel == 2) { g = g2; tgt = t2; }
  if (sel == 3) tgt = 0;
  if (sel == 0 && w == skipw) tgt = 0;
  const unsigned* p = fl + (g * 16 + w) * 8;
  const bool need = tgt > 0;
  for (;;) {
    int ok = 1;
    if (need) ok = ((int)poll_flag(p) >= tgt);
    if (__all(ok)) break;
    __builtin_amdgcn_s_sleep(1);
  }
}

__global__ void diag_kernel(float* out, float code) {
  if (threadIdx.x == 0 && blockIdx.x == 0) out[0] = code;
}

// ---------- prep: zero flags + h planes, build x-features, mirror done ----------
__global__ void prep_kernel(const float* __restrict__ rew, const float* __restrict__ done,
                            const float* __restrict__ gamma, const float* __restrict__ prob,
                            const float* __restrict__ y, const float* __restrict__ y1,
                            const float* __restrict__ w_e1, const float* __restrict__ b_e1,
                            const float* __restrict__ w_e2, const float* __restrict__ b_e2,
                            char* __restrict__ ws) {
  unsigned* zbase = (unsigned*)ws;
  float* donef = (float*)(ws + DONEF_OFF);
  float* xfeat = (float*)(ws + XF_OFF);

  __shared__ float we1[480], be1[16], we2[16];
  __shared__ float be2s, gam;
  for (int i = threadIdx.x; i < 480; i += blockDim.x) we1[i] = w_e1[i];
  if (threadIdx.x < 16) { be1[threadIdx.x] = b_e1[threadIdx.x]; we2[threadIdx.x] = w_e2[threadIdx.x]; }
  if (threadIdx.x == 0) { be2s = b_e2[0]; gam = gamma[0]; }
  __syncthreads();
  const int gid = blockIdx.x * blockDim.x + threadIdx.x;
  const int stride = gridDim.x * blockDim.x;

  for (int i = gid; i < NZERO_U32; i += stride) zbase[i] = 0u;
  for (int i = gid; i < BDIM * TDIM; i += stride) donef[i] = done[i];

  for (int i = gid; i < BDIM * TDIM; i += stride) {   // i = b*T + t
    float yr[30], y1r[30];
    #pragma unroll
    for (int c = 0; c < 30; ++c) { yr[c] = y[(size_t)i * 30 + c]; y1r[c] = y1[(size_t)i * 30 + c]; }
    float a0 = 0.f, a1 = 0.f;
    #pragma unroll 4
    for (int jm = 0; jm < 16; ++jm) {
      float s0 = be1[jm], s1 = be1[jm];
      #pragma unroll
      for (int c = 0; c < 30; ++c) { float w = we1[jm * 30 + c]; s0 += yr[c] * w; s1 += y1r[c] * w; }
      a0 += fmaxf(s0, 0.f) * we2[jm];
      a1 += fmaxf(s1, 0.f) * we2[jm];
    }
    float* xr = xfeat + (size_t)i * 6;
    xr[0] = rew[i]; xr[1] = done[i]; xr[2] = gam;
    xr[3] = prob[i]; xr[4] = sigm(a0 + be2s); xr[5] = sigm(a1 + be2s);
  }
}

// ---------------- layer WG: dataflow-synchronized MFMA step loop ----------------
// groups: 0=L0, 1=L1, 2=L2, 3=head. flag value = completed steps (s+1).
// Deep ring (RING=14): producer at step s waits consumer flag >= s-RING+1,
// absorbing flag-visibility latency D: period P >= (D+2C)/(RING-1).
template <bool L0T>
__device__ __forceinline__ void layer_body(int l, int js, char* __restrict__ ws,
                                           char* __restrict__ ldsx,
                                           const float* __restrict__ Wh,
                                           const float* __restrict__ Wx,
                                           const float* __restrict__ bi,
                                           const float* __restrict__ bh,
                                           const float* __restrict__ wi0) {
  unsigned short* hd = (unsigned short*)(ws + HD_OFF);
  unsigned* fl = (unsigned*)(ws + FLAGS_OFF);
  const float* donef = (const float*)(ws + DONEF_OFF);
  const float* xfeat = (const float*)(ws + XF_OFF);

  const int tid = threadIdx.x;
  const int wv = tid >> 6, lane = tid & 63, q = lane >> 4, jj = lane & 15;
  const int j = js * 16 + jj;

  const float bi_r = bi[j], bi_z = bi[256 + j], bi_n = bi[512 + j];
  const float bh_r = bh[j], bh_z = bh[256 + j], bh_n = bh[512 + j];

  // Wh (d_in fp32) -> VGPR digit frags (bit-identical to mirror path)
  bf16x8 Bh[3][2][8];
  #pragma unroll
  for (int g = 0; g < 3; ++g)
    #pragma unroll
    for (int it = 0; it < 8; ++it) {
      const float* src = Wh + (size_t)(g * 256 + j) * 256 + it * 32 + q * 8;
      #pragma unroll
      for (int e = 0; e < 8; ++e) {
        const float w = src[e];
        const unsigned short d1 = f2bf(w);
        const unsigned short d2 = f2bf(w - bf2f(d1));
        Bh[g][0][it][e] = (short)d1;
        Bh[g][1][it][e] = (short)d2;
      }
    }

  // Wx -> LDS digit frags (l>0)
  if (!L0T) {
    for (int idx = tid; idx < 12288; idx += 256) {
      const int row = idx >> 8, k = idx & 255;
      const int g = row >> 4, jr = row & 15;
      const float w = Wx[(size_t)(g * 256 + js * 16 + jr) * 256 + k];
      const unsigned short d1 = f2bf(w);
      const unsigned short d2 = f2bf(w - bf2f(d1));
      const int it = k >> 5, kk = k & 31;
      *(unsigned short*)(ldsx + ((g * 2 + 0) * 8 + it) * 1280 + jr * 80 + kk * 2) = d1;
      *(unsigned short*)(ldsx + ((g * 2 + 1) * 8 + it) * 1280 + jr * 80 + kk * 2) = d2;
    }
  }
  __syncthreads();

  float wx0[3][6];
  if (L0T) {
    #pragma unroll
    for (int g = 0; g < 3; ++g)
      #pragma unroll
      for (int c = 0; c < 6; ++c) wx0[g][c] = wi0[(g * 256 + j) * 6 + c];
  }

  float hc[8];                     // WG-private fp32 carry
  #pragma unroll
  for (int i = 0; i < 8; ++i) hc[i] = 0.f;

  const int mA0 = (wv * 2) * 16 + jj;
  const f32x4 z4 = {0.f, 0.f, 0.f, 0.f};

  for (int s = 0; s < 1024; ++s) {
    const int t = 1023 - s;
    const int pc = s % RING, pp = (s + RING - 1) % RING;

    // prefetch done factors before the wait
    float sFv[2][4];
    #pragma unroll
    for (int mt = 0; mt < 2; ++mt)
      #pragma unroll
      for (int i = 0; i < 4; ++i)
        sFv[mt][i] = 1.f - donef[((wv * 2 + mt) * 16 + q * 4 + i) * TDIM + t];

    // dataflow waits:
    //  own layer done s-1: flag[l] >= s (own js auto-true)
    //  producer fresh:     flag[l-1] >= s+1
    //  consumer backpressure (deep ring): flag[next] >= s-RING+1
    if (L0T)         wave_wait(fl, 0, s, 1, s - (RING - 1), 1, 0,            js);
    else if (l == 1) wave_wait(fl, 1, s, 0, s + 1,          2, s - (RING - 1), js);
    else             wave_wait(fl, 2, s, 1, s + 1,          3, s - (RING - 1), js);
    asm volatile("" ::: "memory");

    const unsigned short* hh1 = hd + (size_t)((l * RING + pp) * 2 + 0) * SLOT;
    const unsigned short* hh2 = hd + (size_t)((l * RING + pp) * 2 + 1) * SLOT;
    const unsigned short* hx1 = L0T ? (const unsigned short*)0 : hd + (size_t)(((l - 1) * RING + pc) * 2 + 0) * SLOT;
    const unsigned short* hx2 = L0T ? (const unsigned short*)0 : hd + (size_t)(((l - 1) * RING + pc) * 2 + 1) * SLOT;
    unsigned short* hdw1 = hd + (size_t)((l * RING + pc) * 2 + 0) * SLOT;
    unsigned short* hdw2 = hd + (size_t)((l * RING + pc) * 2 + 1) * SLOT;

    f32x4 Ch[2][3], Cx[2][3];
    #pragma unroll
    for (int mt = 0; mt < 2; ++mt)
      #pragma unroll
      for (int g = 0; g < 3; ++g) { Ch[mt][g] = z4; Cx[mt][g] = z4; }

    #pragma unroll
    for (int it = 0; it < 8; ++it) {
      const int koff = it * 32 + q * 8;
      bf16x8 a1[2], a2[2], x1[2], x2[2];
      #pragma unroll
      for (int mt = 0; mt < 2; ++mt) {
        const int mA = mA0 + mt * 16;
        a1[mt] = ld_frag_coh(hh1 + (size_t)mA * 256 + koff);
        a2[mt] = ld_frag_coh(hh2 + (size_t)mA * 256 + koff);
        if (!L0T) {
          x1[mt] = ld_frag_coh(hx1 + (size_t)mA * 256 + koff);
          x2[mt] = ld_frag_coh(hx2 + (size_t)mA * 256 + koff);
        }
      }
      #pragma unroll
      for (int g = 0; g < 3; ++g) {
        #pragma unroll
        for (int dig = 0; dig < 2; ++dig) {
          const bf16x8 wb = Bh[g][dig][it];
          #pragma unroll
          for (int mt = 0; mt < 2; ++mt) {
            Ch[mt][g] = __builtin_amdgcn_mfma_f32_16x16x32_bf16(a1[mt], wb, Ch[mt][g], 0, 0, 0);
            Ch[mt][g] = __builtin_amdgcn_mfma_f32_16x16x32_bf16(a2[mt], wb, Ch[mt][g], 0, 0, 0);
          }
          if (!L0T) {
            const bf16x8 xb = *(const bf16x8*)(ldsx + ((g * 2 + dig) * 8 + it) * 1280 + jj * 80 + q * 16);
            #pragma unroll
            for (int mt = 0; mt < 2; ++mt) {
              Cx[mt][g] = __builtin_amdgcn_mfma_f32_16x16x32_bf16(x1[mt], xb, Cx[mt][g], 0, 0, 0);
              Cx[mt][g] = __builtin_amdgcn_mfma_f32_16x16x32_bf16(x2[mt], xb, Cx[mt][g], 0, 0, 0);
            }
          }
        }
      }
    }

    // epilogue (verified; C/D layout row=q*4+i, col=jj)
    #pragma unroll
    for (int mt = 0; mt < 2; ++mt) {
      #pragma unroll
      for (int i = 0; i < 4; ++i) {
        const int mC = (wv * 2 + mt) * 16 + q * 4 + i;
        const float sF = sFv[mt][i];
        float gxr, gxz, gxn;
        if (L0T) {
          const float* xr = xfeat + ((size_t)mC * TDIM + t) * 6;
          gxr = 0.f; gxz = 0.f; gxn = 0.f;
          #pragma unroll
          for (int c = 0; c < 6; ++c) {
            const float xv = xr[c];
            gxr += xv * wx0[0][c]; gxz += xv * wx0[1][c]; gxn += xv * wx0[2][c];
          }
        } else {
          gxr = Cx[mt][0][i]; gxz = Cx[mt][1][i]; gxn = Cx[mt][2][i];
        }
        const float r = sigm(gxr + bi_r + sF * Ch[mt][0][i] + bh_r);
        const float z = sigm(gxz + bi_z + sF * Ch[mt][1][i] + bh_z);
        const float n = tanha(gxn + bi_n + r * (sF * Ch[mt][2][i] + bh_n));
        const float hp = hc[mt * 4 + i] * sF;
        const float hv = (1.f - z) * n + z * hp;
        hc[mt * 4 + i] = hv;
        // lane-pair pack (R12-proven): even jj stores d1-plane u32 pair,
        // odd jj stores d2-plane u32 pair — plane layout unchanged.
        const unsigned short d1 = f2bf(hv);
        const unsigned short d2 = f2bf(hv - bf2f(d1));
        const int o1 = __shfl_xor((int)d1, 1, 64);
        const int o2 = __shfl_xor((int)d2, 1, 64);
        const unsigned val = (jj & 1) ? ((unsigned)(o2 & 0xffff) | ((unsigned)d2 << 16))
                                      : ((unsigned)d1 | ((unsigned)(o1 & 0xffff) << 16));
        unsigned short* bp = ((jj & 1) ? hdw2 : hdw1) + (size_t)mC * 256 + (j & ~1);
        st_u32_coh(bp, val);
      }
    }

    // drain stores, WG barrier, flag post
    asm volatile("s_waitcnt vmcnt(0)" ::: "memory");
    __syncthreads();
    if (tid == 0) post_flag(fl, l, js, s + 1);
  }
}

// ---------------- head WGs: digit-plane reconstruct via LDS, fp32 dot ----------------
__device__ __forceinline__ void head_body(int hw, char* __restrict__ ws, float* __restrict__ out,
                                          char* __restrict__ lds,
                                          const float* __restrict__ wfy,
                                          const float* __restrict__ bfy,
                                          const float* __restrict__ wfp,
                                          const float* __restrict__ bfp) {
  const unsigned short* hd = (const unsigned short*)(ws + HD_OFF);
  unsigned* fl = (unsigned*)(ws + FLAGS_OFF);
  float* hlds = (float*)lds;        // 8 rows x 256 f32 = 8KB

  const int tid = threadIdx.x;
  const int d = tid & 31;           // 0..29 yo, 30 pi, 31 idle
  const int bb = tid >> 5;          // 0..7
  const int b = hw * 8 + bb;
  const bool act = d < 31;
  const float* wrow = (d < 30) ? (wfy + d * 256) : wfp;
  const float biasv = (d < 30) ? bfy[d] : bfp[0];

  for (int s = 0; s < 1024; ++s) {
    const int t = 1023 - s;
    const int pc = s % RING;
    wave_wait(fl, 2, s + 1, 0, 0, 0, 0, -1);
    asm volatile("" ::: "memory");

    // stage 8 rows: reconstruct h = d1 + d2 into LDS (err ~2^-18 — negligible)
    {
      const size_t rowoff = (size_t)(hw * 8 + (tid >> 5)) * 256 + (tid & 31) * 8;
      const unsigned short* p1 = hd + (size_t)((2 * RING + pc) * 2 + 0) * SLOT + rowoff;
      const unsigned short* p2 = hd + (size_t)((2 * RING + pc) * 2 + 1) * SLOT + rowoff;
      unsigned long long q10 = ld_u64_coh(p1);
      unsigned long long q11 = ld_u64_coh(p1 + 4);
      unsigned long long q20 = ld_u64_coh(p2);
      unsigned long long q21 = ld_u64_coh(p2 + 4);
      float* dst = hlds + (tid >> 5) * 256 + (tid & 31) * 8;
      #pragma unroll
      for (int e = 0; e < 4; ++e) {
        dst[e]     = bf2f((unsigned short)(q10 >> (16 * e))) + bf2f((unsigned short)(q20 >> (16 * e)));
        dst[4 + e] = bf2f((unsigned short)(q11 >> (16 * e))) + bf2f((unsigned short)(q21 >> (16 * e)));
      }
    }
    __syncthreads();
    if (act) {
      const float* hr = hlds + bb * 256;
      float a0 = 0.f, a1 = 0.f;
      #pragma unroll 8
      for (int kk = 0; kk < 256; kk += 8) {
        const f32x4 h0 = *(const f32x4*)(hr + kk);
        const f32x4 h1 = *(const f32x4*)(hr + kk + 4);
        const f32x4 w0 = *(const f32x4*)(wrow + kk);
        const f32x4 w1 = *(const f32x4*)(wrow + kk + 4);
        a0 += h0[0]*w0[0] + h0[1]*w0[1] + h0[2]*w0[2] + h0[3]*w0[3];
        a1 += h1[0]*w1[0] + h1[1]*w1[1] + h1[2]*w1[2] + h1[3]*w1[3];
      }
      const float acc = a0 + a1;
      if (d < 30) out[BDIM * TDIM + ((size_t)b * TDIM + t) * 30 + d] = sigm(acc + biasv);
      else        out[(size_t)b * TDIM + t] = acc + biasv;
    }
    __syncthreads();   // all lanes done with hlds + slot before consume-signal
    if (tid == 0) post_flag(fl, 3, hw, s + 1);
  }
}

__global__ void __launch_bounds__(256, 1) gru_main(char* __restrict__ ws,
                                                   float* __restrict__ out,
                                                   const float* __restrict__ wi0,
                                                   const float* __restrict__ wh0,
                                                   const float* __restrict__ bi0,
                                                   const float* __restrict__ bh0,
                                                   const float* __restrict__ wi1,
                                                   const float* __restrict__ wh1,
                                                   const float* __restrict__ bi1,
                                                   const float* __restrict__ bh1,
                                                   const float* __restrict__ wi2,
                                                   const float* __restrict__ wh2,
                                                   const float* __restrict__ bi2,
                                                   const float* __restrict__ bh2,
                                                   const float* __restrict__ wfy,
                                                   const float* __restrict__ bfy,
                                                   const float* __restrict__ wfp,
                                                   const float* __restrict__ bfp) {
  __shared__ char ldsx[61440];
  const int bid = blockIdx.x;
  if (bid < 48) {
    const int l = bid >> 4;
    const int js = bid & 15;
    const float* Wh = (l == 0) ? wh0 : (l == 1) ? wh1 : wh2;
    const float* Wx = (l == 0) ? (const float*)0 : (l == 1) ? wi1 : wi2;
    const float* bi = (l == 0) ? bi0 : (l == 1) ? bi1 : bi2;
    const float* bh = (l == 0) ? bh0 : (l == 1) ? bh1 : bh2;
    if (l == 0) layer_body<true>(l, js, ws, ldsx, Wh, Wx, bi, bh, wi0);
    else        layer_body<false>(l, js, ws, ldsx, Wh, Wx, bi, bh, wi0);
  } else {
    head_body(bid - 48, ws, out, ldsx, wfy, bfy, wfp, bfp);
  }
}

extern "C" void kernel_launch(void* const* d_in, const int* in_sizes, int n_in,
                              void* d_out, int out_size, void* d_ws, size_t ws_size,
                              hipStream_t stream) {
  static const int EXP_SIZES[26] = {131072, 131072, 1, 131072, 3932160, 3932160,
                                    4608, 196608, 768, 768,
                                    196608, 196608, 768, 768,
                                    196608, 196608, 768, 768,
                                    7680, 30, 256, 1, 480, 16, 16, 1};
  float code = 0.f;
  if (n_in != 26) code = 900.f;
  if (code == 0.f) {
    for (int i = 0; i < 26; ++i)
      if (in_sizes[i] != EXP_SIZES[i]) { code = 100.f + 4.f * (float)i; break; }
  }
  if (code == 0.f && out_size != 4063232) code = 400.f;
  if (code == 0.f && ws_size < (size_t)WS_NEEDED) code = 300.f;
  if (code != 0.f) {
    diag_kernel<<<1, 64, 0, stream>>>((float*)d_out, code);
    return;
  }

  char* ws = (char*)d_ws;
  prep_kernel<<<512, 256, 0, stream>>>(
      (const float*)d_in[0], (const float*)d_in[1], (const float*)d_in[2],
      (const float*)d_in[3], (const float*)d_in[4], (const float*)d_in[5],
      (const float*)d_in[22], (const float*)d_in[23], (const float*)d_in[24], (const float*)d_in[25],
      ws);
  gru_main<<<NWG_TOTAL, 256, 0, stream>>>(
      ws, (float*)d_out,
      (const float*)d_in[6], (const float*)d_in[7], (const float*)d_in[8], (const float*)d_in[9],
      (const float*)d_in[10], (const float*)d_in[11], (const float*)d_in[12], (const float*)d_in[13],
      (const float*)d_in[14], (const float*)d_in[15], (const float*)d_in[16], (const float*)d_in[17],
      (const float*)d_in[18], (const float*)d_in[19], (const float*)d_in[20], (const float*)d_in[21]);
}